// Round 1
// baseline (1541.557 us; speedup 1.0000x reference)
//
#include <hip/hip_runtime.h>
#include <math.h>

#define NB 16
#define NA 720
#define ND 1024
#define NH 512
#define NW 512

// ---------------------------------------------------------------------------
// Kernel 0: per-angle cos/sin table (matches jnp.linspace(0, pi, A, endpoint=False))
// ---------------------------------------------------------------------------
__global__ __launch_bounds__(256) void angle_kernel(float2* __restrict__ cs) {
    int a = blockIdx.x * 256 + threadIdx.x;
    if (a < NA) {
        const float step = (float)(M_PI / (double)NA);
        float ang = (float)a * step;
        float s, c;
        sincosf(ang, &s, &c);
        cs[a] = make_float2(c, s);
    }
}

// ---------------------------------------------------------------------------
// Kernel 1: ramp filter via in-LDS Stockham radix-2 FFT (fp32).
// One block per (b,a) row. ortho-fft * filt * ortho-ifft == (1/N)*IDFT(filt*DFT(x)).
// ---------------------------------------------------------------------------
__global__ __launch_bounds__(256) void filter_kernel(const float* __restrict__ sino,
                                                     const float* __restrict__ filt,
                                                     float* __restrict__ outp) {
    __shared__ float2 bufA[ND];
    __shared__ float2 bufB[ND];
    __shared__ float2 tw[ND / 2];   // tw[m] = exp(-2*pi*i*m/ND)

    const int tid = threadIdx.x;
    const size_t row = blockIdx.x;
    const float* __restrict__ x = sino + row * ND;
    float* __restrict__ y = outp + row * ND;

    #pragma unroll
    for (int i = 0; i < ND; i += 256)
        bufA[i + tid] = make_float2(x[i + tid], 0.0f);
    #pragma unroll
    for (int i = 0; i < ND / 2; i += 256) {
        int m = i + tid;
        float ang = (float)(-2.0 * M_PI / (double)ND) * (float)m;
        float s, c;
        sincosf(ang, &s, &c);
        tw[m] = make_float2(c, s);
    }
    __syncthreads();

    float2* src = bufA;
    float2* dst = bufB;

    // forward FFT: Stockham, Ns = 1..512
    for (int Ns = 1; Ns < ND; Ns <<= 1) {
        #pragma unroll
        for (int q = 0; q < ND / 2; q += 256) {
            int j = q + tid;
            int m = j & (Ns - 1);
            float2 v0 = src[j];
            float2 v1 = src[j + ND / 2];
            float2 w = tw[m * (ND / 2 / Ns)];
            float tr = w.x * v1.x - w.y * v1.y;
            float ti = w.x * v1.y + w.y * v1.x;
            int d = ((j & ~(Ns - 1)) << 1) + m;
            dst[d]      = make_float2(v0.x + tr, v0.y + ti);
            dst[d + Ns] = make_float2(v0.x - tr, v0.y - ti);
        }
        __syncthreads();
        float2* tmp = src; src = dst; dst = tmp;
    }

    // multiply by (real) filter
    #pragma unroll
    for (int i = 0; i < ND; i += 256) {
        float f = filt[i + tid];
        src[i + tid].x *= f;
        src[i + tid].y *= f;
    }
    __syncthreads();

    // inverse FFT: same flow with conjugated twiddles
    for (int Ns = 1; Ns < ND; Ns <<= 1) {
        #pragma unroll
        for (int q = 0; q < ND / 2; q += 256) {
            int j = q + tid;
            int m = j & (Ns - 1);
            float2 v0 = src[j];
            float2 v1 = src[j + ND / 2];
            float2 w = tw[m * (ND / 2 / Ns)];
            float tr = w.x * v1.x + w.y * v1.y;   // conj(w)*v1
            float ti = w.x * v1.y - w.y * v1.x;
            int d = ((j & ~(Ns - 1)) << 1) + m;
            dst[d]      = make_float2(v0.x + tr, v0.y + ti);
            dst[d + Ns] = make_float2(v0.x - tr, v0.y - ti);
        }
        __syncthreads();
        float2* tmp = src; src = dst; dst = tmp;
    }

    const float inv = 1.0f / (float)ND;
    #pragma unroll
    for (int i = 0; i < ND; i += 256)
        y[i + tid] = src[i + tid].x * inv;
}

// ---------------------------------------------------------------------------
// Kernel 2: backprojection. 64x64 pixel tile per 256-thread block, 16 px/thread.
// Each angle's row staged in LDS as pairs (f[i], f[i+1]) -> one ds_read_b64/sample.
// ---------------------------------------------------------------------------
__global__ __launch_bounds__(256) void backproj_kernel(const float* __restrict__ filtered,
                                                       const float2* __restrict__ cs_tab,
                                                       float* __restrict__ img) {
    __shared__ float2 pair[ND];   // 8 KB
    __shared__ float2 lcs[NA];    // 5.76 KB

    const int tid = threadIdx.x;
    const int bx = blockIdx.x;
    const int by = blockIdx.y;
    const int b  = blockIdx.z;

    for (int i = tid; i < NA; i += 256) lcs[i] = cs_tab[i];

    const int tx  = tid & 63;          // x within tile
    const int ty0 = (tid >> 6) * 16;   // first y within tile (16 consecutive rows)
    const float px  = (float)(bx * 64 + tx)  - 255.5f;
    const float py0 = (float)(by * 64 + ty0) - 255.5f;

    float acc[16];
    #pragma unroll
    for (int k = 0; k < 16; k++) acc[k] = 0.0f;

    const float* __restrict__ base = filtered + (size_t)b * NA * ND;
    const int i4 = tid * 4;
    __syncthreads();

    for (int a = 0; a < NA; a++) {
        const float4 v  = *(const float4*)(base + (size_t)a * ND + i4);
        const float nxt = base[(size_t)a * ND + min(i4 + 4, ND - 1)];
        pair[i4 + 0] = make_float2(v.x, v.y);
        pair[i4 + 1] = make_float2(v.y, v.z);
        pair[i4 + 2] = make_float2(v.z, v.w);
        pair[i4 + 3] = make_float2(v.w, nxt);
        __syncthreads();

        const float2 cs = lcs[a];
        const float tb = px * cs.x + 511.5f;
        #pragma unroll
        for (int k = 0; k < 16; k++) {
            float py = py0 + (float)k;
            float t  = tb + py * cs.y;
            float fi = floorf(t);
            float w  = t - fi;
            int   i0 = (int)fi;
            int   ic = min(max(i0, 0), ND - 2);
            float2 p = pair[ic];
            float val = fmaf(w, p.y - p.x, p.x);
            acc[k] += ((unsigned)i0 <= (unsigned)(ND - 2)) ? val : 0.0f;
        }
        __syncthreads();
    }

    const float scale = (float)(M_PI / (double)NA);
    #pragma unroll
    for (int k = 0; k < 16; k++) {
        const int yy = by * 64 + ty0 + k;
        img[(((size_t)b * NH) + yy) * NW + (bx * 64 + tx)] = acc[k] * scale;
    }
}

// ---------------------------------------------------------------------------
extern "C" void kernel_launch(void* const* d_in, const int* in_sizes, int n_in,
                              void* d_out, int out_size, void* d_ws, size_t ws_size,
                              hipStream_t stream) {
    const float* sino = (const float*)d_in[0];
    const float* filt = (const float*)d_in[1];
    float* out = (float*)d_out;

    const size_t filt_bytes = (size_t)NB * NA * ND * sizeof(float);
    float* filtered;
    float2* cs_tab;
    if (ws_size >= filt_bytes + 4096) {
        filtered = (float*)d_ws;
        cs_tab = (float2*)((char*)d_ws + filt_bytes);
    } else {
        // fallback: filter in-place into the input (harness restores inputs
        // from a pristine copy before every launch)
        filtered = (float*)d_in[0];
        cs_tab = (float2*)d_ws;
    }

    angle_kernel<<<dim3(3), dim3(256), 0, stream>>>(cs_tab);
    filter_kernel<<<dim3(NB * NA), dim3(256), 0, stream>>>(sino, filt, filtered);
    backproj_kernel<<<dim3(NW / 64, NH / 64, NB), dim3(256), 0, stream>>>(filtered, cs_tab, out);
}

// Round 2
// 835.164 us; speedup vs baseline: 1.8458x; 1.8458x over previous
//
#include <hip/hip_runtime.h>
#include <math.h>

#define NB 16
#define NA 720
#define ND 1024
#define NH 512
#define NW 512

// ---------------------------------------------------------------------------
// Kernel 0: per-angle cos/sin table (matches jnp.linspace(0, pi, A, endpoint=False))
// ---------------------------------------------------------------------------
__global__ __launch_bounds__(256) void angle_kernel(float2* __restrict__ cs) {
    int a = blockIdx.x * 256 + threadIdx.x;
    if (a < NA) {
        const float step = (float)(M_PI / (double)NA);
        float ang = (float)a * step;
        float s, c;
        sincosf(ang, &s, &c);
        cs[a] = make_float2(c, s);
    }
}

// ---------------------------------------------------------------------------
// Kernel 1: ramp filter via in-LDS Stockham radix-2 FFT (fp32).
// One block per (b,a) row. ortho-fft * filt * ortho-ifft == (1/N)*IDFT(filt*DFT(x)).
// ---------------------------------------------------------------------------
__global__ __launch_bounds__(256) void filter_kernel(const float* __restrict__ sino,
                                                     const float* __restrict__ filt,
                                                     float* __restrict__ outp) {
    __shared__ float2 bufA[ND];
    __shared__ float2 bufB[ND];
    __shared__ float2 tw[ND / 2];   // tw[m] = exp(-2*pi*i*m/ND)

    const int tid = threadIdx.x;
    const size_t row = blockIdx.x;
    const float* __restrict__ x = sino + row * ND;
    float* __restrict__ y = outp + row * ND;

    #pragma unroll
    for (int i = 0; i < ND; i += 256)
        bufA[i + tid] = make_float2(x[i + tid], 0.0f);
    #pragma unroll
    for (int i = 0; i < ND / 2; i += 256) {
        int m = i + tid;
        float ang = (float)(-2.0 * M_PI / (double)ND) * (float)m;
        float s, c;
        sincosf(ang, &s, &c);
        tw[m] = make_float2(c, s);
    }
    __syncthreads();

    float2* src = bufA;
    float2* dst = bufB;

    // forward FFT: Stockham, Ns = 1..512
    for (int Ns = 1; Ns < ND; Ns <<= 1) {
        #pragma unroll
        for (int q = 0; q < ND / 2; q += 256) {
            int j = q + tid;
            int m = j & (Ns - 1);
            float2 v0 = src[j];
            float2 v1 = src[j + ND / 2];
            float2 w = tw[m * (ND / 2 / Ns)];
            float tr = w.x * v1.x - w.y * v1.y;
            float ti = w.x * v1.y + w.y * v1.x;
            int d = ((j & ~(Ns - 1)) << 1) + m;
            dst[d]      = make_float2(v0.x + tr, v0.y + ti);
            dst[d + Ns] = make_float2(v0.x - tr, v0.y - ti);
        }
        __syncthreads();
        float2* tmp = src; src = dst; dst = tmp;
    }

    // multiply by (real) filter
    #pragma unroll
    for (int i = 0; i < ND; i += 256) {
        float f = filt[i + tid];
        src[i + tid].x *= f;
        src[i + tid].y *= f;
    }
    __syncthreads();

    // inverse FFT: same flow with conjugated twiddles
    for (int Ns = 1; Ns < ND; Ns <<= 1) {
        #pragma unroll
        for (int q = 0; q < ND / 2; q += 256) {
            int j = q + tid;
            int m = j & (Ns - 1);
            float2 v0 = src[j];
            float2 v1 = src[j + ND / 2];
            float2 w = tw[m * (ND / 2 / Ns)];
            float tr = w.x * v1.x + w.y * v1.y;   // conj(w)*v1
            float ti = w.x * v1.y - w.y * v1.x;
            int d = ((j & ~(Ns - 1)) << 1) + m;
            dst[d]      = make_float2(v0.x + tr, v0.y + ti);
            dst[d + Ns] = make_float2(v0.x - tr, v0.y - ti);
        }
        __syncthreads();
        float2* tmp = src; src = dst; dst = tmp;
    }

    const float inv = 1.0f / (float)ND;
    #pragma unroll
    for (int i = 0; i < ND; i += 256)
        y[i + tid] = src[i + tid].x * inv;
}

// ---------------------------------------------------------------------------
// Kernel 2: backprojection. 64x64 pixel tile per 256-thread block, 16 px/thread.
// Per angle, only a <=92-entry detector window is touched by the tile:
//   span = 63*(|c|+|s|) + lerp guard <= 63*sqrt(2)+3 < 128.
// Stage a 128-entry (f[i], f[i+1]) pair window, ping-pong double-buffered,
// ONE barrier per angle. Bounds check eliminated: |px*c+py*s| <= 361.3 < 511.5
// so t in [150, 873] always; window index in [1, 93] subset of [0,127].
// ---------------------------------------------------------------------------
__global__ __launch_bounds__(256) void backproj_kernel(const float* __restrict__ filtered,
                                                       const float2* __restrict__ cs_tab,
                                                       float* __restrict__ img) {
    __shared__ float2 win[2][128];   // 2 KB total

    const int tid = threadIdx.x;
    const int bx = blockIdx.x;
    const int by = blockIdx.y;
    const int b  = blockIdx.z;

    const int tx  = tid & 63;          // x within tile (lane -> consecutive x)
    const int ty0 = (tid >> 6) * 16;   // first y within tile
    const float px  = (float)(bx * 64 + tx)  - 255.5f;
    const float py0 = (float)(by * 64 + ty0) - 255.5f;

    const float x0 = (float)(bx * 64) - 255.5f;
    const float x1 = x0 + 63.0f;
    const float y0 = (float)(by * 64) - 255.5f;

    const float* __restrict__ rowb = filtered + (size_t)b * NA * ND;

    float acc[16];
    #pragma unroll
    for (int k = 0; k < 16; k++) acc[k] = 0.0f;

    // window base for angle a (uniform across block): floor(min_t) - 1
    // s >= 0 for all angles in [0, pi), so min over py is at y0.
    auto calc_base = [&](float2 cs) -> int {
        float tmin = 511.5f + fminf(x0 * cs.x, x1 * cs.x) + y0 * cs.y;
        return (int)floorf(tmin) - 1;
    };

    // prologue: stage angle 0
    float2 cs = cs_tab[0];
    int base = calc_base(cs);
    if (tid < 128) {
        const float* r = rowb + base + tid;
        win[0][tid] = make_float2(r[0], r[1]);
    }
    __syncthreads();

    for (int a = 0; a < NA; a++) {
        // issue next angle's staging load early (hidden behind compute)
        float2 csn;
        int basen = 0;
        float v0 = 0.0f, v1 = 0.0f;
        if (a + 1 < NA) {
            csn = cs_tab[a + 1];
            basen = calc_base(csn);
            if (tid < 128) {
                const float* r = rowb + (size_t)(a + 1) * ND + basen + tid;
                v0 = r[0];
                v1 = r[1];
            }
        }

        const float2* __restrict__ w0 = win[a & 1];
        // t_local = px*c + py*s + 511.5 - base, computed at small magnitude
        const float tb2 = fmaf(px, cs.x, fmaf(py0, cs.y, 511.5f - (float)base));
        const float sy = cs.y;
        #pragma unroll
        for (int k = 0; k < 16; k++) {
            float t  = fmaf((float)k, sy, tb2);
            int   i0 = (int)t;                       // t > 0 -> trunc == floor
#if __has_builtin(__builtin_amdgcn_fractf)
            float w  = __builtin_amdgcn_fractf(t);   // t - floor(t), 1 op
#else
            float w  = t - (float)i0;
#endif
            float2 p = w0[i0];
            acc[k] = fmaf(w, p.y - p.x, acc[k] + p.x);
        }

        if (a + 1 < NA) {
            if (tid < 128) win[(a + 1) & 1][tid] = make_float2(v0, v1);
            cs = csn;
            base = basen;
        }
        __syncthreads();
    }

    const float scale = (float)(M_PI / (double)NA);
    #pragma unroll
    for (int k = 0; k < 16; k++) {
        const int yy = by * 64 + ty0 + k;
        img[(((size_t)b * NH) + yy) * NW + (bx * 64 + tx)] = acc[k] * scale;
    }
}

// ---------------------------------------------------------------------------
extern "C" void kernel_launch(void* const* d_in, const int* in_sizes, int n_in,
                              void* d_out, int out_size, void* d_ws, size_t ws_size,
                              hipStream_t stream) {
    const float* sino = (const float*)d_in[0];
    const float* filt = (const float*)d_in[1];
    float* out = (float*)d_out;

    const size_t filt_bytes = (size_t)NB * NA * ND * sizeof(float);
    float* filtered;
    float2* cs_tab;
    if (ws_size >= filt_bytes + 4096) {
        filtered = (float*)d_ws;
        cs_tab = (float2*)((char*)d_ws + filt_bytes);
    } else {
        // fallback: filter in-place into the input (harness restores inputs
        // from a pristine copy before every launch)
        filtered = (float*)d_in[0];
        cs_tab = (float2*)d_ws;
    }

    angle_kernel<<<dim3(3), dim3(256), 0, stream>>>(cs_tab);
    filter_kernel<<<dim3(NB * NA), dim3(256), 0, stream>>>(sino, filt, filtered);
    backproj_kernel<<<dim3(NW / 64, NH / 64, NB), dim3(256), 0, stream>>>(filtered, cs_tab, out);
}

// Round 3
// 819.944 us; speedup vs baseline: 1.8801x; 1.0186x over previous
//
#include <hip/hip_runtime.h>
#include <math.h>

#define NB 16
#define NA 720
#define ND 1024
#define NH 512
#define NW 512

// ---------------------------------------------------------------------------
// Kernel 0: per-angle cos/sin table (matches jnp.linspace(0, pi, A, endpoint=False))
// ---------------------------------------------------------------------------
__global__ __launch_bounds__(256) void angle_kernel(float2* __restrict__ cs) {
    int a = blockIdx.x * 256 + threadIdx.x;
    if (a < NA) {
        const float step = (float)(M_PI / (double)NA);
        float ang = (float)a * step;
        float s, c;
        sincosf(ang, &s, &c);
        cs[a] = make_float2(c, s);
    }
}

// ---------------------------------------------------------------------------
// Kernel 1: ramp filter via in-LDS Stockham radix-2 FFT (fp32).
// One block per (b,a) row. ortho-fft * filt * ortho-ifft == (1/N)*IDFT(filt*DFT(x)).
// ---------------------------------------------------------------------------
__global__ __launch_bounds__(256) void filter_kernel(const float* __restrict__ sino,
                                                     const float* __restrict__ filt,
                                                     float* __restrict__ outp) {
    __shared__ float2 bufA[ND];
    __shared__ float2 bufB[ND];
    __shared__ float2 tw[ND / 2];   // tw[m] = exp(-2*pi*i*m/ND)

    const int tid = threadIdx.x;
    const size_t row = blockIdx.x;
    const float* __restrict__ x = sino + row * ND;
    float* __restrict__ y = outp + row * ND;

    #pragma unroll
    for (int i = 0; i < ND; i += 256)
        bufA[i + tid] = make_float2(x[i + tid], 0.0f);
    #pragma unroll
    for (int i = 0; i < ND / 2; i += 256) {
        int m = i + tid;
        float ang = (float)(-2.0 * M_PI / (double)ND) * (float)m;
        float s, c;
        sincosf(ang, &s, &c);
        tw[m] = make_float2(c, s);
    }
    __syncthreads();

    float2* src = bufA;
    float2* dst = bufB;

    // forward FFT: Stockham, Ns = 1..512
    for (int Ns = 1; Ns < ND; Ns <<= 1) {
        #pragma unroll
        for (int q = 0; q < ND / 2; q += 256) {
            int j = q + tid;
            int m = j & (Ns - 1);
            float2 v0 = src[j];
            float2 v1 = src[j + ND / 2];
            float2 w = tw[m * (ND / 2 / Ns)];
            float tr = w.x * v1.x - w.y * v1.y;
            float ti = w.x * v1.y + w.y * v1.x;
            int d = ((j & ~(Ns - 1)) << 1) + m;
            dst[d]      = make_float2(v0.x + tr, v0.y + ti);
            dst[d + Ns] = make_float2(v0.x - tr, v0.y - ti);
        }
        __syncthreads();
        float2* tmp = src; src = dst; dst = tmp;
    }

    // multiply by (real) filter
    #pragma unroll
    for (int i = 0; i < ND; i += 256) {
        float f = filt[i + tid];
        src[i + tid].x *= f;
        src[i + tid].y *= f;
    }
    __syncthreads();

    // inverse FFT: same flow with conjugated twiddles
    for (int Ns = 1; Ns < ND; Ns <<= 1) {
        #pragma unroll
        for (int q = 0; q < ND / 2; q += 256) {
            int j = q + tid;
            int m = j & (Ns - 1);
            float2 v0 = src[j];
            float2 v1 = src[j + ND / 2];
            float2 w = tw[m * (ND / 2 / Ns)];
            float tr = w.x * v1.x + w.y * v1.y;   // conj(w)*v1
            float ti = w.x * v1.y - w.y * v1.x;
            int d = ((j & ~(Ns - 1)) << 1) + m;
            dst[d]      = make_float2(v0.x + tr, v0.y + ti);
            dst[d + Ns] = make_float2(v0.x - tr, v0.y - ti);
        }
        __syncthreads();
        float2* tmp = src; src = dst; dst = tmp;
    }

    const float inv = 1.0f / (float)ND;
    #pragma unroll
    for (int i = 0; i < ND; i += 256)
        y[i + tid] = src[i + tid].x * inv;
}

// ---------------------------------------------------------------------------
// Kernel 2: backprojection. 64x32 pixel tile per 256-thread block, 8 px/thread.
// Grid = 2048 blocks -> 8 blocks/CU -> 32 waves/CU (100% occupancy cap) for
// DS/VALU overlap. Per angle the tile touches a <=80-entry detector window:
//   span = 63|c| + 31|s| + guard <= sqrt(63^2+31^2)+4 < 128.
// Window staged PRE-DIFFERENCED: win[i] = (f[i], f[i+1]-f[i]) so the inner
// loop is: t=fma, i0=cvt, w=fract, addr, ds_read_b64, acc=fma(w,df,acc+f)
// = 6 VALU + 1 DS per sample. Bounds check eliminated (|t-511.5|<=361.3).
// ---------------------------------------------------------------------------
__global__ __launch_bounds__(256, 8) void backproj_kernel(const float* __restrict__ filtered,
                                                          const float2* __restrict__ cs_tab,
                                                          float* __restrict__ img) {
    __shared__ float2 win[2][128];   // 2 KB total

    const int tid = threadIdx.x;
    const int bx = blockIdx.x;
    const int by = blockIdx.y;
    const int b  = blockIdx.z;

    const int tx  = tid & 63;         // x within tile (lane -> consecutive x)
    const int ty0 = (tid >> 6) * 8;   // first y within tile
    const float px  = (float)(bx * 64 + tx)  - 255.5f;
    const float py0 = (float)(by * 32 + ty0) - 255.5f;

    const float x0 = (float)(bx * 64) - 255.5f;
    const float x1 = x0 + 63.0f;
    const float y0 = (float)(by * 32) - 255.5f;

    const float* __restrict__ rowb = filtered + (size_t)b * NA * ND;

    float acc[8];
    #pragma unroll
    for (int k = 0; k < 8; k++) acc[k] = 0.0f;

    // window base for angle a (uniform across block): floor(min_t) - 1
    // s >= 0 for all angles in [0, pi), so min over py is at y0.
    auto calc_base = [&](float2 cs) -> int {
        float tmin = 511.5f + fminf(x0 * cs.x, x1 * cs.x) + y0 * cs.y;
        return (int)floorf(tmin) - 1;
    };

    // prologue: stage angle 0 (pre-differenced)
    float2 cs = cs_tab[0];
    int base = calc_base(cs);
    if (tid < 128) {
        const float* r = rowb + base + tid;
        float f0 = r[0], f1 = r[1];
        win[0][tid] = make_float2(f0, f1 - f0);
    }
    __syncthreads();

    for (int a = 0; a < NA; a++) {
        // issue next angle's staging load early (hidden behind compute)
        float2 csn;
        int basen = 0;
        float v0 = 0.0f, v1 = 0.0f;
        if (a + 1 < NA) {
            csn = cs_tab[a + 1];
            basen = calc_base(csn);
            if (tid < 128) {
                const float* r = rowb + (size_t)(a + 1) * ND + basen + tid;
                v0 = r[0];
                v1 = r[1];
            }
        }

        const float2* __restrict__ w0 = win[a & 1];
        // t_local = px*c + py*s + 511.5 - base, computed at small magnitude
        const float tb2 = fmaf(px, cs.x, fmaf(py0, cs.y, 511.5f - (float)base));
        const float sy = cs.y;
        #pragma unroll
        for (int k = 0; k < 8; k++) {
            float t  = fmaf((float)k, sy, tb2);
            int   i0 = (int)t;                       // t > 0 -> trunc == floor
#if __has_builtin(__builtin_amdgcn_fractf)
            float w  = __builtin_amdgcn_fractf(t);   // t - floor(t), 1 op
#else
            float w  = t - (float)i0;
#endif
            float2 p = w0[i0];                        // (f, f[i+1]-f[i])
            acc[k] = fmaf(w, p.y, acc[k] + p.x);
        }

        if (a + 1 < NA) {
            if (tid < 128) win[(a + 1) & 1][tid] = make_float2(v0, v1 - v0);
            cs = csn;
            base = basen;
        }
        __syncthreads();
    }

    const float scale = (float)(M_PI / (double)NA);
    #pragma unroll
    for (int k = 0; k < 8; k++) {
        const int yy = by * 32 + ty0 + k;
        img[(((size_t)b * NH) + yy) * NW + (bx * 64 + tx)] = acc[k] * scale;
    }
}

// ---------------------------------------------------------------------------
extern "C" void kernel_launch(void* const* d_in, const int* in_sizes, int n_in,
                              void* d_out, int out_size, void* d_ws, size_t ws_size,
                              hipStream_t stream) {
    const float* sino = (const float*)d_in[0];
    const float* filt = (const float*)d_in[1];
    float* out = (float*)d_out;

    const size_t filt_bytes = (size_t)NB * NA * ND * sizeof(float);
    float* filtered;
    float2* cs_tab;
    if (ws_size >= filt_bytes + 4096) {
        filtered = (float*)d_ws;
        cs_tab = (float2*)((char*)d_ws + filt_bytes);
    } else {
        // fallback: filter in-place into the input (harness restores inputs
        // from a pristine copy before every launch)
        filtered = (float*)d_in[0];
        cs_tab = (float2*)d_ws;
    }

    angle_kernel<<<dim3(3), dim3(256), 0, stream>>>(cs_tab);
    filter_kernel<<<dim3(NB * NA), dim3(256), 0, stream>>>(sino, filt, filtered);
    backproj_kernel<<<dim3(NW / 64, NH / 32, NB), dim3(256), 0, stream>>>(filtered, cs_tab, out);
}

// Round 4
// 698.904 us; speedup vs baseline: 2.2057x; 1.1732x over previous
//
#include <hip/hip_runtime.h>
#include <math.h>

#define NB 16
#define NA 720
#define ND 1024
#define NH 512
#define NW 512

#define TW 64      // tile width  (x)
#define TH 16      // tile height (y)
#define PXT 4      // y-pixels per thread
#define WINN 96    // detector window entries per batch (span <= 67 for 64x16 tile)

// ---------------------------------------------------------------------------
// Kernel 0: per-angle cos/sin table (matches jnp.linspace(0, pi, A, endpoint=False))
// ---------------------------------------------------------------------------
__global__ __launch_bounds__(256) void angle_kernel(float2* __restrict__ cs) {
    int a = blockIdx.x * 256 + threadIdx.x;
    if (a < NA) {
        const float step = (float)(M_PI / (double)NA);
        float ang = (float)a * step;
        float s, c;
        sincosf(ang, &s, &c);
        cs[a] = make_float2(c, s);
    }
}

// ---------------------------------------------------------------------------
// Kernel 1: ramp filter via in-LDS Stockham radix-2 FFT (fp32), TWO real rows
// per block packed as z = x0 + i*x1. Filter is real & even-symmetric, so
// Y = filt*Z directly; IFFT gives y0 = Re, y1 = Im. Scale pi/(NA*ND) folded in.
// ---------------------------------------------------------------------------
__global__ __launch_bounds__(256) void filter_kernel(const float* __restrict__ sino,
                                                     const float* __restrict__ filt,
                                                     float* __restrict__ outp) {
    __shared__ float2 bufA[ND];
    __shared__ float2 bufB[ND];
    __shared__ float2 tw[ND / 2];   // tw[m] = exp(-2*pi*i*m/ND)

    const int tid = threadIdx.x;
    const size_t r0 = (size_t)blockIdx.x * 2;
    const float* __restrict__ xa = sino + r0 * ND;
    const float* __restrict__ xb = xa + ND;
    float* __restrict__ ya = outp + r0 * ND;
    float* __restrict__ yb = ya + ND;

    #pragma unroll
    for (int i = 0; i < ND; i += 256)
        bufA[i + tid] = make_float2(xa[i + tid], xb[i + tid]);
    #pragma unroll
    for (int i = 0; i < ND / 2; i += 256) {
        int m = i + tid;
        float ang = (float)(-2.0 * M_PI / (double)ND) * (float)m;
        float s, c;
        sincosf(ang, &s, &c);
        tw[m] = make_float2(c, s);
    }
    __syncthreads();

    float2* src = bufA;
    float2* dst = bufB;

    // forward FFT: Stockham, Ns = 1..512
    for (int Ns = 1; Ns < ND; Ns <<= 1) {
        #pragma unroll
        for (int q = 0; q < ND / 2; q += 256) {
            int j = q + tid;
            int m = j & (Ns - 1);
            float2 v0 = src[j];
            float2 v1 = src[j + ND / 2];
            float2 w = tw[m * (ND / 2 / Ns)];
            float tr = w.x * v1.x - w.y * v1.y;
            float ti = w.x * v1.y + w.y * v1.x;
            int d = ((j & ~(Ns - 1)) << 1) + m;
            dst[d]      = make_float2(v0.x + tr, v0.y + ti);
            dst[d + Ns] = make_float2(v0.x - tr, v0.y - ti);
        }
        __syncthreads();
        float2* tmp = src; src = dst; dst = tmp;
    }

    // multiply by real filter, with pi/(NA*ND) folded in
    const float SCALE = (float)(M_PI / ((double)NA * (double)ND));
    #pragma unroll
    for (int i = 0; i < ND; i += 256) {
        float f = filt[i + tid] * SCALE;
        src[i + tid].x *= f;
        src[i + tid].y *= f;
    }
    __syncthreads();

    // inverse FFT: same flow with conjugated twiddles
    for (int Ns = 1; Ns < ND; Ns <<= 1) {
        #pragma unroll
        for (int q = 0; q < ND / 2; q += 256) {
            int j = q + tid;
            int m = j & (Ns - 1);
            float2 v0 = src[j];
            float2 v1 = src[j + ND / 2];
            float2 w = tw[m * (ND / 2 / Ns)];
            float tr = w.x * v1.x + w.y * v1.y;   // conj(w)*v1
            float ti = w.x * v1.y - w.y * v1.x;
            int d = ((j & ~(Ns - 1)) << 1) + m;
            dst[d]      = make_float2(v0.x + tr, v0.y + ti);
            dst[d + Ns] = make_float2(v0.x - tr, v0.y - ti);
        }
        __syncthreads();
        float2* tmp = src; src = dst; dst = tmp;
    }

    #pragma unroll
    for (int i = 0; i < ND; i += 256) {
        ya[i + tid] = src[i + tid].x;   // row r0   (Re)
        yb[i + tid] = src[i + tid].y;   // row r0+1 (Im)
    }
}

// ---------------------------------------------------------------------------
// Kernel 2: backprojection. 64x16 pixel tile x 2 BATCHES per 256-thread block
// (4 y-px * 2 b = 8 acc/thread). Geometry (t,i0,w,addr) shared across the 2
// batches -> ~4 VALU + 1 ds_read_b64 per sample. Per-angle params precomputed
// into an LDS float4 table (c, s, 511.5-base, a*ND+base). Ping-pong window
// phase is compile-time (angle loop unrolled x2) so ds_read uses imm offsets.
// Bounds check eliminated: |px*c+py*s| <= 361.3 < 511.5 always in-range.
// ---------------------------------------------------------------------------
__global__ __launch_bounds__(256, 8) void backproj_kernel(const float* __restrict__ filtered,
                                                          const float2* __restrict__ cs_tab,
                                                          float* __restrict__ img) {
    __shared__ float4 params[NA];          // 11.25 KB
    __shared__ float2 win[2][2 * WINN];    // 3 KB: [phase][b*WINN + idx], pre-differenced

    const int tid = threadIdx.x;
    const int bx = blockIdx.x, by = blockIdx.y, bz = blockIdx.z;

    const float x0 = (float)(bx * TW) - 255.5f;
    const float x1 = x0 + (float)(TW - 1);
    const float y0 = (float)(by * TH) - 255.5f;

    // per-angle parameter table (s >= 0 for angles in [0,pi): min over y at y0)
    for (int a = tid; a < NA; a += 256) {
        float2 cs = cs_tab[a];
        float tmin = 511.5f + fminf(x0 * cs.x, x1 * cs.x) + y0 * cs.y;
        int base = (int)floorf(tmin) - 1;
        params[a] = make_float4(cs.x, cs.y, 511.5f - (float)base,
                                __int_as_float(a * ND + base));
    }

    // staging mapping: threads 0..95 -> batch0, 96..191 -> batch1
    const bool stg = tid < 2 * WINN;
    const int sb   = (tid >= WINN) ? 1 : 0;
    const int sidx = tid - sb * WINN;
    const float* __restrict__ srow =
        filtered + (size_t)(bz * 2 + sb) * NA * ND + sidx;
    const int wslot = sb * WINN + sidx;

    const int tx  = tid & (TW - 1);
    const int ty0 = (tid / TW) * PXT;
    const float px  = (float)(bx * TW + tx)  - 255.5f;
    const float pyf = (float)(by * TH + ty0) - 255.5f;

    float acc0[PXT], acc1[PXT];
    #pragma unroll
    for (int k = 0; k < PXT; k++) { acc0[k] = 0.0f; acc1[k] = 0.0f; }

    __syncthreads();   // params ready

    // prologue: stage angle 0 into phase 0
    float4 P = params[0];
    if (stg) {
        int soff = __float_as_int(P.w);
        float f0 = srow[soff], f1 = srow[soff + 1];
        win[0][wslot] = make_float2(f0, f1 - f0);
    }
    __syncthreads();

    for (int a0 = 0; a0 < NA; a0 += 2) {
        #pragma unroll
        for (int p = 0; p < 2; p++) {
            const int a = a0 + p;
            float4 Pn = P;
            float f0 = 0.0f, f1 = 0.0f;
            const bool pre = (a + 1 < NA);
            if (pre) {
                Pn = params[a + 1];
                if (stg) {
                    int soff = __float_as_int(Pn.w);
                    f0 = srow[soff];
                    f1 = srow[soff + 1];
                }
            }

            const float sy = P.y;
            const float tb = fmaf(px, P.x, fmaf(pyf, sy, P.z));
            #pragma unroll
            for (int k = 0; k < PXT; k++) {
                float t  = fmaf((float)k, sy, tb);
                int   i0 = (int)t;                       // t > 0 -> trunc == floor
#if __has_builtin(__builtin_amdgcn_fractf)
                float w  = __builtin_amdgcn_fractf(t);
#else
                float w  = t - (float)i0;
#endif
                float2 q0 = win[p][i0];                  // batch0 (f, df)
                float2 q1 = win[p][i0 + WINN];           // batch1 (f, df)
                acc0[k] = fmaf(w, q0.y, acc0[k] + q0.x);
                acc1[k] = fmaf(w, q1.y, acc1[k] + q1.x);
            }

            if (pre && stg)
                win[p ^ 1][wslot] = make_float2(f0, f1 - f0);
            P = Pn;
            __syncthreads();
        }
    }

    // epilogue (scale already folded into the filter)
    size_t o0 = (((size_t)(bz * 2) * NH) + (by * TH + ty0)) * NW + (bx * TW + tx);
    size_t o1 = o0 + (size_t)NH * NW;
    #pragma unroll
    for (int k = 0; k < PXT; k++) {
        img[o0 + (size_t)k * NW] = acc0[k];
        img[o1 + (size_t)k * NW] = acc1[k];
    }
}

// ---------------------------------------------------------------------------
extern "C" void kernel_launch(void* const* d_in, const int* in_sizes, int n_in,
                              void* d_out, int out_size, void* d_ws, size_t ws_size,
                              hipStream_t stream) {
    const float* sino = (const float*)d_in[0];
    const float* filt = (const float*)d_in[1];
    float* out = (float*)d_out;

    const size_t filt_bytes = (size_t)NB * NA * ND * sizeof(float);
    float* filtered;
    float2* cs_tab;
    if (ws_size >= filt_bytes + 4096) {
        filtered = (float*)d_ws;
        cs_tab = (float2*)((char*)d_ws + filt_bytes);
    } else {
        // fallback: filter in-place into the input (harness restores inputs
        // from a pristine copy before every launch)
        filtered = (float*)d_in[0];
        cs_tab = (float2*)d_ws;
    }

    angle_kernel<<<dim3(3), dim3(256), 0, stream>>>(cs_tab);
    filter_kernel<<<dim3(NB * NA / 2), dim3(256), 0, stream>>>(sino, filt, filtered);
    backproj_kernel<<<dim3(NW / TW, NH / TH, NB / 2), dim3(256), 0, stream>>>(filtered, cs_tab, out);
}